// Round 13
// baseline (113.276 us; speedup 1.0000x reference)
//
#include <hip/hip_runtime.h>
#include <hip/hip_bf16.h>

#define N 8192
#define FIN 128
#define FOUT 64
#define CSPLIT 2
#define CHUNK (N / CSPLIT)     // 4096 cols per block
#define M 32                   // rows per block
#define TILE 128               // cols per tile
#define NT (CHUNK / TILE)      // 32 tiles
#define LOG2E 1.44269504f

typedef __attribute__((ext_vector_type(4))) float f32x4;
typedef __attribute__((ext_vector_type(4))) int i32x4;
typedef __attribute__((ext_vector_type(8))) short bf16x8;

#define GLOAD_LDS16(gp, lp)                                                    \
    __builtin_amdgcn_global_load_lds(                                          \
        (const __attribute__((address_space(1))) void*)(gp),                   \
        (__attribute__((address_space(3))) void*)(lp), 16, 0, 0)

// Kernel 1: Wh = h @ W (W staged once per 16 rows), s_src/s_dst pre-scaled by log2e.
__global__ __launch_bounds__(256) void wh_kernel(
    const float* __restrict__ h, const float* __restrict__ W,
    const float* __restrict__ a,
    __hip_bfloat16* __restrict__ whT, float* __restrict__ s_src,
    float* __restrict__ s_dst) {
    __shared__ float Wl[FIN * FOUT];              // 32 KB
    const int w = threadIdx.x >> 6;
    const int lane = threadIdx.x & 63;            // lane = output feature f
#pragma unroll
    for (int q = 0; q < 8; ++q) {
        const int i = w * 8 + q;
        GLOAD_LDS16(W + i * 256 + lane * 4, &Wl[i * 256]);
    }
    asm volatile("s_waitcnt vmcnt(0)" ::: "memory");
    __syncthreads();

    const int rbase = blockIdx.x * 16 + w * 4;    // 4 rows per wave
    float acc[4] = {0.f, 0.f, 0.f, 0.f};
    for (int k0 = 0; k0 < FIN; k0 += 4) {
        float wv0 = Wl[(k0 + 0) * FOUT + lane];
        float wv1 = Wl[(k0 + 1) * FOUT + lane];
        float wv2 = Wl[(k0 + 2) * FOUT + lane];
        float wv3 = Wl[(k0 + 3) * FOUT + lane];
#pragma unroll
        for (int rr = 0; rr < 4; ++rr) {
            f32x4 hv = *(const f32x4*)(h + (size_t)(rbase + rr) * FIN + k0);
            acc[rr] += hv[0] * wv0 + hv[1] * wv1 + hv[2] * wv2 + hv[3] * wv3;
        }
    }
#pragma unroll
    for (int rr = 0; rr < 4; ++rr) {
        const int row = rbase + rr;
        whT[(size_t)lane * N + row] = __float2bfloat16(acc[rr]);
        float s1 = acc[rr] * a[lane];
        float s2 = acc[rr] * a[FOUT + lane];
#pragma unroll
        for (int mm = 32; mm >= 1; mm >>= 1) {
            s1 += __shfl_xor(s1, mm, 64);
            s2 += __shfl_xor(s2, mm, 64);
        }
        if (lane == 0) { s_src[row] = s1 * LOG2E; s_dst[row] = s2 * LOG2E; }
    }
}

// Kernel 2: fused masked-softmax attention partials.
//   adj: triple-buffered LDS stream (stage distance 3 -> 2 compute phases of cover)
//   whT B-fragments: register pipeline from L2 (distance 2, asm loads, counted vmcnt)
//   inner loop: R10/R11 VALU diet. Issue order B-then-adj => FIFO vmcnt 8/6/0.
//   FIX vs R12: acc4 (denominator, ones-MFMA) is its OWN statement/register --
//   no acc[3] reuse (R12's comma-juggle corrupted features 48..63).
__global__ __launch_bounds__(512, 4) void gat_partial(
    const int* __restrict__ adj, const __hip_bfloat16* __restrict__ whT,
    const float* __restrict__ s_src, const float* __restrict__ s_dst,
    float* __restrict__ numP, float* __restrict__ denP) {
    union SMem {
        struct {
            int adjb[3][M][TILE];       // 48 KB (swizzled rows of 512B)
            float sdl[CHUNK];           // 16 KB
        } s;                            // 64 KB
        struct { float pC[4][M][FOUT]; float pD[4][M]; } e;  // 33 KB
    };
    __shared__ SMem sm;

    const int tid = threadIdx.x;
    const int w = tid >> 6, lane = tid & 63;
    const int m = lane & 15, kg = lane >> 4;
    const int wr = w >> 2, wc = w & 3;
    const int rg = blockIdx.x >> 1;
    const int c = blockIdx.x & 1;
    const int ibase = rg * M;
    const int cb = c * CHUNK;
    const int aRow = wr * 16 + m;
    const float ssrc = s_src[ibase + aRow];       // pre-scaled by log2e
    const int sidx = w * 2;
    const int bcol = wc * 32 + kg * 8;            // this lane's B-frag col base

    f32x4 acc[4] = {{0,0,0,0},{0,0,0,0},{0,0,0,0},{0,0,0,0}};
    f32x4 acc4 = {0,0,0,0};
    const short oneb = (m == 0) ? (short)0x3F80 : (short)0;
    const bf16x8 bones = {oneb, oneb, oneb, oneb, oneb, oneb, oneb, oneb};

    bf16x8 rb0_0, rb0_1, rb0_2, rb0_3;            // B-frag register sets
    bf16x8 rb1_0, rb1_1, rb1_2, rb1_3;

#define STGA(T) do {                                                           \
    const int gcol_ = cb + (T) * TILE;                                         \
    _Pragma("unroll") for (int q_ = 0; q_ < 2; ++q_) {                         \
        const int idx_ = sidx + q_;                                            \
        const int r_ = idx_ * 2 + (lane >> 5);                                 \
        const int b_ = ((lane & 31) * 16) ^ ((r_ & 31) << 4);                  \
        GLOAD_LDS16(adj + (size_t)(ibase + r_) * N + gcol_ + (b_ >> 2),        \
                    &sm.s.adjb[(T) % 3][idx_ * 2][0]);                         \
    } } while (0)

#define LDB(S, T) do {                                                         \
    asm volatile("global_load_dwordx4 %0, %1, off" : "=v"(rb##S##_0)           \
        : "v"(whT + (size_t)(0 * 16 + m) * N + cb + (T) * TILE + bcol));       \
    asm volatile("global_load_dwordx4 %0, %1, off" : "=v"(rb##S##_1)           \
        : "v"(whT + (size_t)(1 * 16 + m) * N + cb + (T) * TILE + bcol));       \
    asm volatile("global_load_dwordx4 %0, %1, off" : "=v"(rb##S##_2)           \
        : "v"(whT + (size_t)(2 * 16 + m) * N + cb + (T) * TILE + bcol));       \
    asm volatile("global_load_dwordx4 %0, %1, off" : "=v"(rb##S##_3)           \
        : "v"(whT + (size_t)(3 * 16 + m) * N + cb + (T) * TILE + bcol));       \
    } while (0)

#define WAITB(CNT, NS)                                                         \
    asm volatile("s_waitcnt vmcnt(" CNT ")"                                    \
        : "+v"(rb##NS##_0), "+v"(rb##NS##_1), "+v"(rb##NS##_2),                \
          "+v"(rb##NS##_3) :: "memory");                                       \
    __builtin_amdgcn_sched_barrier(0)

    // prologue: sdl(2) adj0(2) B0(4) adj1(2) B1(4) adj2(2) -> wait vmcnt(8)
#pragma unroll
    for (int q = 0; q < 2; ++q) {
        const int idx = sidx + q;
        GLOAD_LDS16(s_dst + cb + idx * 256 + lane * 4, &sm.s.sdl[idx * 256]);
    }
    STGA(0); LDB(0, 0); STGA(1); LDB(1, 1); STGA(2);
    WAITB("8", 0);
    __builtin_amdgcn_s_barrier();

#define BODY(T, S, NS) do {                                                    \
    const int t_ = (T);                                                        \
    {                                                                          \
        const char* adjbase = ((const char*)sm.s.adjb) + (t_ % 3) * (M * TILE * 4); \
        const int aswz = (aRow & 31) << 4;                                     \
        const int kcol = bcol;                                                 \
        i32x4 a0 = *(const i32x4*)(adjbase + aRow * 512 + ((kcol * 4) ^ aswz)); \
        i32x4 a1 = *(const i32x4*)(adjbase + aRow * 512 + ((kcol * 4 + 16) ^ aswz)); \
        f32x4 d0 = *(const f32x4*)&sm.s.sdl[t_ * TILE + kcol];                 \
        f32x4 d1 = *(const f32x4*)&sm.s.sdl[t_ * TILE + kcol + 4];             \
        float p[8];                                                            \
        _Pragma("unroll") for (int e = 0; e < 4; ++e) {                        \
            float x = ssrc + d0[e];                                            \
            float xl = fmaxf(x, 0.2f * x);                                     \
            float pe;                                                          \
            asm("v_exp_f32 %0, %1" : "=v"(pe) : "v"(xl));                      \
            p[e] = (a0[e] != 0) ? pe : 0.f;                                    \
        }                                                                      \
        _Pragma("unroll") for (int e = 0; e < 4; ++e) {                        \
            float x = ssrc + d1[e];                                            \
            float xl = fmaxf(x, 0.2f * x);                                     \
            float pe;                                                          \
            asm("v_exp_f32 %0, %1" : "=v"(pe) : "v"(xl));                      \
            p[4 + e] = (a1[e] != 0) ? pe : 0.f;                                \
        }                                                                      \
        union { bf16x8 v; unsigned u[4]; } afr;                                \
        _Pragma("unroll") for (int q_ = 0; q_ < 4; ++q_) {                     \
            asm("v_cvt_pk_bf16_f32 %0, %1, %2"                                 \
                : "=v"(afr.u[q_]) : "v"(p[2 * q_]), "v"(p[2 * q_ + 1]));       \
        }                                                                      \
        acc[0] = __builtin_amdgcn_mfma_f32_16x16x32_bf16(afr.v, rb##S##_0, acc[0], 0, 0, 0); \
        acc[1] = __builtin_amdgcn_mfma_f32_16x16x32_bf16(afr.v, rb##S##_1, acc[1], 0, 0, 0); \
        acc[2] = __builtin_amdgcn_mfma_f32_16x16x32_bf16(afr.v, rb##S##_2, acc[2], 0, 0, 0); \
        acc[3] = __builtin_amdgcn_mfma_f32_16x16x32_bf16(afr.v, rb##S##_3, acc[3], 0, 0, 0); \
        acc4   = __builtin_amdgcn_mfma_f32_16x16x32_bf16(afr.v, bones, acc4, 0, 0, 0); \
    }                                                                          \
    __builtin_amdgcn_s_barrier();                                              \
    if (t_ + 2 < NT) LDB(S, t_ + 2);                                           \
    if (t_ + 3 < NT) STGA(t_ + 3);                                             \
    if (t_ + 3 < NT)      { WAITB("8", NS); }                                  \
    else if (t_ + 2 < NT) { WAITB("6", NS); }                                  \
    else if (t_ + 1 < NT) { WAITB("0", NS); }                                  \
    if (t_ + 1 < NT) __builtin_amdgcn_s_barrier();                             \
    } while (0)

    for (int tt = 0; tt < NT; tt += 2) {
        BODY(tt, 0, 1);
        BODY(tt + 1, 1, 0);
    }

#undef BODY
#undef WAITB
#undef LDB
#undef STGA

    __syncthreads();   // all waves done with adjb/sdl -> union reuse safe

#pragma unroll
    for (int r = 0; r < 4; ++r) {
#pragma unroll
        for (int q = 0; q < 4; ++q) {
            sm.e.pC[wc][wr * 16 + kg * 4 + r][q * 16 + m] = acc[q][r];
        }
    }
    if (m == 0) {   // den (col 0 of ones-MFMA): m==0 lanes, row kg*4+r
#pragma unroll
        for (int r = 0; r < 4; ++r) {
            sm.e.pD[wc][wr * 16 + kg * 4 + r] = acc4[r];
        }
    }
    __syncthreads();

    float* numC = numP + (size_t)c * N * FOUT;
    float* denC = denP + (size_t)c * N;
#pragma unroll
    for (int k = 0; k < 4; ++k) {
        int idx = k * 512 + tid;
        int i = idx >> 6, f = idx & 63;
        float num = sm.e.pC[0][i][f] + sm.e.pC[1][i][f] + sm.e.pC[2][i][f] + sm.e.pC[3][i][f];
        numC[(size_t)(ibase + i) * FOUT + f] = num;
        if (f == 0) {
            denC[ibase + i] = sm.e.pD[0][i] + sm.e.pD[1][i] + sm.e.pD[2][i] + sm.e.pD[3][i];
        }
    }
}

// Kernel 3: sum chunk partials, divide, ELU, store.
__global__ __launch_bounds__(256) void gat_combine(
    const float* __restrict__ numP, const float* __restrict__ denP,
    float* __restrict__ out) {
    int idx = blockIdx.x * 256 + threadIdx.x;
    int row = idx >> 6;
    float num = 0.f, den = 0.f;
#pragma unroll
    for (int cc = 0; cc < CSPLIT; ++cc) {
        num += numP[(size_t)cc * N * FOUT + idx];
        den += denP[(size_t)cc * N + row];
    }
    float v = num / den;
    out[idx] = (v > 0.f) ? v : expm1f(v);
}

extern "C" void kernel_launch(void* const* d_in, const int* in_sizes, int n_in,
                              void* d_out, int out_size, void* d_ws, size_t ws_size,
                              hipStream_t stream) {
    const float* h = (const float*)d_in[0];
    const int* adj = (const int*)d_in[1];
    const float* W = (const float*)d_in[2];
    const float* a = (const float*)d_in[3];
    float* out = (float*)d_out;

    char* ws = (char*)d_ws;
    __hip_bfloat16* whT = (__hip_bfloat16*)ws;                       // 1 MB
    float* s_src = (float*)(ws + (size_t)FOUT * N * sizeof(__hip_bfloat16));
    float* s_dst = s_src + N;
    float* numP = s_dst + N;                                         // 4 MB
    float* denP = numP + (size_t)CSPLIT * N * FOUT;                  // 64 KB

    hipLaunchKernelGGL(wh_kernel, dim3(N / 16), dim3(256), 0, stream,
                       h, W, a, whT, s_src, s_dst);
    hipLaunchKernelGGL(gat_partial, dim3((N / M) * CSPLIT), dim3(512), 0, stream,
                       adj, whT, s_src, s_dst, numP, denP);
    hipLaunchKernelGGL(gat_combine, dim3(N * FOUT / 256), dim3(256), 0, stream,
                       numP, denP, out);
}